// Round 15
// baseline (151.856 us; speedup 1.0000x reference)
//
#include <hip/hip_runtime.h>
#include <math.h>

typedef __bf16 bf16x8 __attribute__((ext_vector_type(8)));
typedef float f32x4 __attribute__((ext_vector_type(4)));

namespace {
constexpr int DIMC = 1024, NH = 16, HD = 64, SEQ = 2048;
constexpr float SCL2 = 0.1803368801f;  // 1/(tau*sqrt(64)) * log2(e), folded into Q
}

__device__ __forceinline__ unsigned short f2b(float f) {
  unsigned u = __float_as_uint(f);
  return (unsigned short)((u + 0x7fffu + ((u >> 16) & 1u)) >> 16);
}
__device__ __forceinline__ float b2f(unsigned short s) {
  return __uint_as_float((unsigned)s << 16);
}
__device__ __forceinline__ unsigned cvtpk(float lo, float hi) {
  unsigned r;
  asm("v_cvt_pk_bf16_f32 %0, %1, %2" : "=v"(r) : "v"(lo), "v"(hi));
  return r;
}
__device__ __forceinline__ void gld16(void* l, const void* g) {
  __builtin_amdgcn_global_load_lds(
      (const __attribute__((address_space(1))) void*)g,
      (__attribute__((address_space(3))) void*)l, 16, 0, 0);
}

// fp32 -> bf16 (RNE), 8 elements per thread
__global__ __launch_bounds__(256)
void cvt_bf16(const float* __restrict__ in, unsigned short* __restrict__ out, int n8) {
  int i = blockIdx.x * 256 + threadIdx.x;
  if (i >= n8) return;
  const float4* in4 = (const float4*)in;
  float4 a = in4[2 * i], b = in4[2 * i + 1];
  union { unsigned short u[8]; uint4 v; } r;
  r.u[0] = f2b(a.x); r.u[1] = f2b(a.y); r.u[2] = f2b(a.z); r.u[3] = f2b(a.w);
  r.u[4] = f2b(b.x); r.u[5] = f2b(b.y); r.u[6] = f2b(b.z); r.u[7] = f2b(b.w);
  ((uint4*)out)[i] = r.v;
}

// weight matrices fp32 -> bf16, outputs contiguous
__global__ __launch_bounds__(256)
void cvt_w4(const float* __restrict__ w0, const float* __restrict__ w1,
            const float* __restrict__ w2, const float* __restrict__ w3,
            unsigned short* __restrict__ out) {
  const int which = blockIdx.y;
  const float* src = which == 0 ? w0 : which == 1 ? w1 : which == 2 ? w2 : w3;
  unsigned short* dst = out + (size_t)which * 1048576;
  int i = blockIdx.x * 256 + threadIdx.x;
  const float4* in4 = (const float4*)src;
  float4 a = in4[2 * i], b = in4[2 * i + 1];
  union { unsigned short u[8]; uint4 v; } r;
  r.u[0] = f2b(a.x); r.u[1] = f2b(a.y); r.u[2] = f2b(a.z); r.u[3] = f2b(a.w);
  r.u[4] = f2b(b.x); r.u[5] = f2b(b.y); r.u[6] = f2b(b.z); r.u[7] = f2b(b.w);
  ((uint4*)dst)[i] = r.v;
}

// ---- m97-structure GEMM tile: BM=BN=128, BK=32, gld16 staging, 16 MFMA/K-step ----
template<int MODE>
__device__ __forceinline__
void gemm_tile128(const unsigned short* __restrict__ A, const unsigned short* __restrict__ W,
                  const float* __restrict__ bias, void* __restrict__ Cout,
                  int bm, int bn, float scl, char* As, char* Bs) {
  const int tid = threadIdx.x, lane = tid & 63, w = tid >> 6;
  const int p = lane & 15, g = lane >> 4;
  const int wr = w >> 1, wc = w & 1;
  const int sr = tid >> 2, sc = (tid & 3) * 8;

  f32x4 acc[4][4];
#pragma unroll
  for (int mf = 0; mf < 4; ++mf)
#pragma unroll
    for (int nf = 0; nf < 4; ++nf)
      acc[mf][nf] = (f32x4){0.f, 0.f, 0.f, 0.f};

  const size_t arow0 = (size_t)(bm + sr) * DIMC + sc;
  const size_t arow1 = (size_t)(bm + 64 + sr) * DIMC + sc;
  const size_t brow0 = (size_t)(bn + sr) * DIMC + sc;
  const size_t brow1 = (size_t)(bn + 64 + sr) * DIMC + sc;

  for (int k0 = 0; k0 < DIMC; k0 += 32) {
    __syncthreads();
    gld16(&As[tid * 16],        &A[arow0 + k0]);
    gld16(&As[4096 + tid * 16], &A[arow1 + k0]);
    gld16(&Bs[tid * 16],        &W[brow0 + k0]);
    gld16(&Bs[4096 + tid * 16], &W[brow1 + k0]);
    __syncthreads();
    bf16x8 af[4], bfr[4];
#pragma unroll
    for (int mf = 0; mf < 4; ++mf)
      af[mf] = *(const bf16x8*)&As[(wr * 64 + mf * 16 + p) * 64 + g * 16];
#pragma unroll
    for (int nf = 0; nf < 4; ++nf)
      bfr[nf] = *(const bf16x8*)&Bs[(wc * 64 + nf * 16 + p) * 64 + g * 16];
#pragma unroll
    for (int mf = 0; mf < 4; ++mf)
#pragma unroll
      for (int nf = 0; nf < 4; ++nf)
        acc[mf][nf] = __builtin_amdgcn_mfma_f32_16x16x32_bf16(af[mf], bfr[nf], acc[mf][nf], 0, 0, 0);
  }

#pragma unroll
  for (int nf = 0; nf < 4; ++nf) {
    const int cg = bn + wc * 64 + nf * 16 + p;
    const float bv = bias[cg & (DIMC - 1)];
#pragma unroll
    for (int mf = 0; mf < 4; ++mf) {
#pragma unroll
      for (int j = 0; j < 4; ++j) {
        const int rg = bm + wr * 64 + mf * 16 + g * 4 + j;
        const float v = (acc[mf][nf][j] + bv) * scl;
        if (MODE == 0) {
          ((float*)Cout)[(size_t)rg * DIMC + cg] = v;
        } else {
          const int bb = rg >> 11, ss = rg & (SEQ - 1);
          const int hh = cg >> 6, dd = cg & (HD - 1);
          ((unsigned short*)Cout)[(((size_t)(bb * NH + hh) * SEQ + ss) * HD) + dd] = f2b(v);
        }
      }
    }
  }
}

// fused Q/K/V projection: grid (32, 8, 3); z selects weight/bias/out.
// Q (z==0) pre-scaled by SCL2 so attention scores land in log2 units.
__global__ __launch_bounds__(256, 2)
void gemm_qkv(const unsigned short* __restrict__ A, const unsigned short* __restrict__ Wall,
              const float* __restrict__ bq, const float* __restrict__ bk,
              const float* __restrict__ bv, unsigned short* __restrict__ Out) {
  __shared__ char As[8192];
  __shared__ char Bs[8192];
  const int which = blockIdx.z;
  const unsigned short* W = Wall + (size_t)which * 1048576;
  const float* bias = which == 0 ? bq : which == 1 ? bk : bv;
  unsigned short* Cout = Out + (size_t)which * 4194304;
  const float scl = which == 0 ? SCL2 : 1.0f;
  gemm_tile128<1>(A, W, bias, Cout, blockIdx.x * 128, blockIdx.y * 128, scl, As, Bs);
}

// ---- gemm_out: 128x64 tile, gld16 staging, 512 blocks = 2/CU ----
__global__ __launch_bounds__(256, 2)
void gemm_out(const unsigned short* __restrict__ A, const unsigned short* __restrict__ W,
              const float* __restrict__ bias, float* __restrict__ Cout) {
  __shared__ char As[8192];  // [128][32] bf16
  __shared__ char Bs[4096];  // [64][32] bf16
  const int tid = threadIdx.x, lane = tid & 63, w = tid >> 6;
  const int p = lane & 15, g = lane >> 4;
  const int wr = w >> 1, wc = w & 1;
  const int bm = blockIdx.x * 128, bn = blockIdx.y * 64;
  const int sr = tid >> 2, sc = (tid & 3) * 8;

  f32x4 acc[4][2];
#pragma unroll
  for (int mf = 0; mf < 4; ++mf)
#pragma unroll
    for (int nf = 0; nf < 2; ++nf)
      acc[mf][nf] = (f32x4){0.f, 0.f, 0.f, 0.f};

  const size_t arow0 = (size_t)(bm + sr) * DIMC + sc;
  const size_t arow1 = (size_t)(bm + 64 + sr) * DIMC + sc;
  const size_t brow  = (size_t)(bn + sr) * DIMC + sc;

  for (int k0 = 0; k0 < DIMC; k0 += 32) {
    __syncthreads();
    gld16(&As[tid * 16],        &A[arow0 + k0]);
    gld16(&As[4096 + tid * 16], &A[arow1 + k0]);
    gld16(&Bs[tid * 16],        &W[brow + k0]);
    __syncthreads();
    bf16x8 af[4], bfr[2];
#pragma unroll
    for (int mf = 0; mf < 4; ++mf)
      af[mf] = *(const bf16x8*)&As[(wr * 64 + mf * 16 + p) * 64 + g * 16];
#pragma unroll
    for (int nf = 0; nf < 2; ++nf)
      bfr[nf] = *(const bf16x8*)&Bs[(wc * 32 + nf * 16 + p) * 64 + g * 16];
#pragma unroll
    for (int mf = 0; mf < 4; ++mf)
#pragma unroll
      for (int nf = 0; nf < 2; ++nf)
        acc[mf][nf] = __builtin_amdgcn_mfma_f32_16x16x32_bf16(af[mf], bfr[nf], acc[mf][nf], 0, 0, 0);
  }

#pragma unroll
  for (int nf = 0; nf < 2; ++nf) {
    const int cg = bn + wc * 32 + nf * 16 + p;
    const float bv = bias[cg];
#pragma unroll
    for (int mf = 0; mf < 4; ++mf) {
#pragma unroll
      for (int j = 0; j < 4; ++j) {
        const int rg = bm + wr * 64 + mf * 16 + g * 4 + j;
        Cout[(size_t)rg * DIMC + cg] = acc[mf][nf][j] + bv;
      }
    }
  }
}

// Fused flash attention — strength-reduced addressing:
// global K/V via per-lane base pointers advanced by constant stride (offsets
// fold to load immediates); all swizzled LDS offsets precomputed once; main
// loop pair-unrolled so buffer parity is a literal (folds to ds offset imm).
__global__ __launch_bounds__(256, 2)
void attn_fused(const unsigned short* __restrict__ Q, const unsigned short* __restrict__ K,
                const unsigned short* __restrict__ V, unsigned short* __restrict__ Y) {
  __shared__ char Vt[2][8192];   // V^T [64 d][64 key] bf16, XOR-swizzled, dbuf
  __shared__ char Pl[2][16384];  // P [128 q][64 key] bf16, XOR-swizzled, dbuf
  const int tid = threadIdx.x, lane = tid & 63, w = tid >> 6;
  const int p = lane & 15, g = lane >> 4;
  const int bh = blockIdx.x, b = bh >> 4, h = bh & 15;
  const int q0 = blockIdx.y * 128, qw = q0 + w * 32;
  const size_t base = (size_t)bh * SEQ * HD;
  const unsigned short* Qp = Q + base;
  const unsigned short* Kp = K + base;
  const unsigned short* Vp = V + base;

  union Vu { bf16x8 v; unsigned short u[8]; };

  // Q fragments (resident whole kernel)
  bf16x8 qf[2][2];
#pragma unroll
  for (int mi = 0; mi < 2; ++mi)
#pragma unroll
    for (int ks = 0; ks < 2; ++ks)
      qf[mi][ks] = *(const bf16x8*)&Qp[(size_t)(qw + mi * 16 + p) * HD + ks * 32 + g * 8];

  bf16x8 ones8;
  {
    union { unsigned short u[8]; bf16x8 v; } o;
#pragma unroll
    for (int e = 0; e < 8; ++e) o.u[e] = (p == 0) ? (unsigned short)0x3F80 : (unsigned short)0;
    ones8 = o.v;
  }

  // ---- strength-reduced global bases (advance by 64*HD elems per tile) ----
  const int kp = tid & 31, vd0 = (tid >> 5) * 8;
  const unsigned short* kA = Kp + (size_t)p * HD + g * 8;          // nf 0,1
  const unsigned short* kB = kA + 2 * 16 * HD;                     // nf 2,3
  const unsigned short* vP = Vp + (size_t)(2 * kp) * HD + vd0;

  // ---- precomputed LDS byte offsets (loop-invariant) ----
  int pwOff[2][4], prOff[2][2], vwOff[8], vrOff[4][2];
#pragma unroll
  for (int mi = 0; mi < 2; ++mi) {
    const int r = w * 32 + mi * 16 + p;
    const int swz = (r & 7) << 4;
#pragma unroll
    for (int nf = 0; nf < 4; ++nf) pwOff[mi][nf] = r * 128 + ((nf * 32 + g * 8) ^ swz);
#pragma unroll
    for (int ks = 0; ks < 2; ++ks) prOff[mi][ks] = r * 128 + ((ks * 64 + g * 16) ^ swz);
  }
#pragma unroll
  for (int e = 0; e < 8; ++e) {
    const int d = vd0 + e;
    vwOff[e] = d * 128 + ((kp * 4) ^ ((d & 7) << 4));
  }
#pragma unroll
  for (int nfd = 0; nfd < 4; ++nfd) {
    const int d = nfd * 16 + p;
    const int swz = (d & 7) << 4;
#pragma unroll
    for (int ks = 0; ks < 2; ++ks) vrOff[nfd][ks] = d * 128 + ((ks * 64 + g * 16) ^ swz);
  }

  f32x4 o2[2][4];
  f32x4 ol[2];
#pragma unroll
  for (int mi = 0; mi < 2; ++mi) {
#pragma unroll
    for (int nf = 0; nf < 4; ++nf)
      o2[mi][nf] = (f32x4){0.f, 0.f, 0.f, 0.f};
    ol[mi] = (f32x4){0.f, 0.f, 0.f, 0.f};
  }

  bf16x8 kf[4][2];
  Vu v0, v1;
  f32x4 s2[2][4];
  unsigned pk[2][8];

  auto loadKV = [&]() {  // const element offsets -> fold into load imm
    kf[0][0] = *(const bf16x8*)(kA + 0);
    kf[0][1] = *(const bf16x8*)(kA + 32);
    kf[1][0] = *(const bf16x8*)(kA + 1024);
    kf[1][1] = *(const bf16x8*)(kA + 1056);
    kf[2][0] = *(const bf16x8*)(kB + 0);
    kf[2][1] = *(const bf16x8*)(kB + 32);
    kf[3][0] = *(const bf16x8*)(kB + 1024);
    kf[3][1] = *(const bf16x8*)(kB + 1056);
    v0.v = *(const bf16x8*)(vP + 0);
    v1.v = *(const bf16x8*)(vP + HD);
    kA += 64 * HD; kB += 64 * HD; vP += 64 * HD;
  };
  auto qkt = [&]() {
#pragma unroll
    for (int mi = 0; mi < 2; ++mi)
#pragma unroll
      for (int nf = 0; nf < 4; ++nf)
        s2[mi][nf] = (f32x4){0.f, 0.f, 0.f, 0.f};
    __builtin_amdgcn_s_setprio(1);
#pragma unroll
    for (int mi = 0; mi < 2; ++mi)
#pragma unroll
      for (int nf = 0; nf < 4; ++nf)
#pragma unroll
        for (int ks = 0; ks < 2; ++ks)
          s2[mi][nf] = __builtin_amdgcn_mfma_f32_16x16x32_bf16(kf[nf][ks], qf[mi][ks], s2[mi][nf], 0, 0, 0);
    __builtin_amdgcn_s_setprio(0);
  };
  auto softmax = [&]() {   // no-max: P = exp2(s2)
#pragma unroll
    for (int mi = 0; mi < 2; ++mi) {
#pragma unroll
      for (int nf = 0; nf < 4; ++nf)
#pragma unroll
        for (int j = 0; j < 4; ++j)
          s2[mi][nf][j] = exp2f(s2[mi][nf][j]);
#pragma unroll
      for (int nf = 0; nf < 4; ++nf) {
        pk[mi][2 * nf]     = cvtpk(s2[mi][nf][0], s2[mi][nf][1]);
        pk[mi][2 * nf + 1] = cvtpk(s2[mi][nf][2], s2[mi][nf][3]);
      }
    }
  };
  auto stage = [&](int par) {   // called with literal par -> folds to imm
    char* plp = &Pl[0][0] + par * 16384;
    char* vtp = &Vt[0][0] + par * 8192;
#pragma unroll
    for (int mi = 0; mi < 2; ++mi)
#pragma unroll
      for (int nf = 0; nf < 4; ++nf) {
        uint2 val; val.x = pk[mi][2 * nf]; val.y = pk[mi][2 * nf + 1];
        *(uint2*)(plp + pwOff[mi][nf]) = val;
      }
#pragma unroll
    for (int e = 0; e < 8; ++e) {
      const unsigned val = (unsigned)v0.u[e] | ((unsigned)v1.u[e] << 16);
      *(unsigned*)(vtp + vwOff[e]) = val;
    }
  };
  auto pv = [&](int par) {
    const char* plp = &Pl[0][0] + par * 16384;
    const char* vtp = &Vt[0][0] + par * 8192;
    bf16x8 pf[2][2], vb[4][2];
#pragma unroll
    for (int mi = 0; mi < 2; ++mi)
#pragma unroll
      for (int ks = 0; ks < 2; ++ks)
        pf[mi][ks] = *(const bf16x8*)(plp + prOff[mi][ks]);
#pragma unroll
    for (int nfd = 0; nfd < 4; ++nfd)
#pragma unroll
      for (int ks = 0; ks < 2; ++ks)
        vb[nfd][ks] = *(const bf16x8*)(vtp + vrOff[nfd][ks]);
    __builtin_amdgcn_s_setprio(1);
#pragma unroll
    for (int mi = 0; mi < 2; ++mi)
#pragma unroll
      for (int nfd = 0; nfd < 4; ++nfd)
#pragma unroll
        for (int ks = 0; ks < 2; ++ks)
          o2[mi][nfd] = __builtin_amdgcn_mfma_f32_16x16x32_bf16(vb[nfd][ks], pf[mi][ks], o2[mi][nfd], 0, 0, 0);
#pragma unroll
    for (int mi = 0; mi < 2; ++mi)
#pragma unroll
      for (int ks = 0; ks < 2; ++ks)
        ol[mi] = __builtin_amdgcn_mfma_f32_16x16x32_bf16(ones8, pf[mi][ks], ol[mi], 0, 0, 0);
    __builtin_amdgcn_s_setprio(0);
  };
  auto tileStep = [&](int parPrev, int parCur) {
    loadKV();          // K(t),V(t) in flight...
    pv(parPrev);       // ...hidden under PV's LDS reads + MFMA
    qkt();
    softmax();
    stage(parCur);
    __syncthreads();
  };

  // prologue: tile 0
  loadKV();
  qkt();
  softmax();
  stage(0);
  __syncthreads();

  // tiles 1..30 in pairs (literal parity), then tile 31
  for (int it = 0; it < 15; ++it) {
    tileStep(0, 1);
    tileStep(1, 0);
  }
  tileStep(0, 1);   // kt = 31
  pv(1);

  // epilogue: out = 0.6*O/l + 0.4*(L@V); l broadcast from (g==0) lanes
  const float e1 = 4.3936934e-2f, e2 = 3.7266532e-6f, e3 = 6.1019804e-13f;
  const float lwv[4] = {1.f, e1, e2, e3};
#pragma unroll
  for (int mi = 0; mi < 2; ++mi) {
    const int q = qw + mi * 16 + p;
    const float lq = __shfl(ol[mi][0], p);   // lane (g=0, p) holds row-0 sum for q
    const float inv = 0.6f / lq;
    float wsum = 0.f;
#pragma unroll
    for (int dd = -3; dd <= 3; ++dd) {
      const int kk = q + dd;
      if (kk >= 0 && kk < SEQ) wsum += lwv[dd < 0 ? -dd : dd];
    }
    const float wn = 0.4f / (wsum + 1e-10f);
#pragma unroll
    for (int nfd = 0; nfd < 4; ++nfd) {
      const int d0 = nfd * 16 + g * 4;
      float loc[4] = {0.f, 0.f, 0.f, 0.f};
#pragma unroll
      for (int dd = -3; dd <= 3; ++dd) {
        const int kk = q + dd;
        if (kk >= 0 && kk < SEQ) {
          const uint2 lv = *(const uint2*)&Vp[(size_t)kk * HD + d0];
          const float wt = lwv[dd < 0 ? -dd : dd];
          loc[0] = fmaf(wt, b2f((unsigned short)lv.x), loc[0]);
          loc[1] = fmaf(wt, b2f((unsigned short)(lv.x >> 16)), loc[1]);
          loc[2] = fmaf(wt, b2f((unsigned short)lv.y), loc[2]);
          loc[3] = fmaf(wt, b2f((unsigned short)(lv.y >> 16)), loc[3]);
        }
      }
      uint2 st;
      st.x = cvtpk(o2[mi][nfd][0] * inv + loc[0] * wn, o2[mi][nfd][1] * inv + loc[1] * wn);
      st.y = cvtpk(o2[mi][nfd][2] * inv + loc[2] * wn, o2[mi][nfd][3] * inv + loc[3] * wn);
      *(uint2*)&Y[((size_t)(b * SEQ + q)) * DIMC + h * HD + d0] = st;
    }
  }
}

extern "C" void kernel_launch(void* const* d_in, const int* in_sizes, int n_in,
                              void* d_out, int out_size, void* d_ws, size_t ws_size,
                              hipStream_t stream) {
  (void)in_sizes; (void)n_in; (void)out_size; (void)ws_size;
  const float* x  = (const float*)d_in[0];
  const float* Wq = (const float*)d_in[1];
  const float* bq = (const float*)d_in[2];
  const float* Wk = (const float*)d_in[3];
  const float* bk = (const float*)d_in[4];
  const float* Wv = (const float*)d_in[5];
  const float* bv = (const float*)d_in[6];
  const float* Wo = (const float*)d_in[7];
  const float* bo = (const float*)d_in[8];

  char* ws = (char*)d_ws;
  unsigned short* xb  = (unsigned short*)(ws);               // 8 MB
  unsigned short* Wqb = (unsigned short*)(ws + 8388608);     // 2 MB each, contiguous
  unsigned short* Wob = (unsigned short*)(ws + 14680064);
  unsigned short* Qh  = (unsigned short*)(ws + 16777216);    // 8 MB each (Q,K,V)
  unsigned short* Kh  = (unsigned short*)(ws + 25165824);
  unsigned short* Vh  = (unsigned short*)(ws + 33554432);
  unsigned short* Yb  = (unsigned short*)(ws + 41943040);    // 8 MB

  dim3 blk(256);
  cvt_bf16<<<2048, blk, 0, stream>>>(x, xb, 524288);
  cvt_w4<<<dim3(512, 4), blk, 0, stream>>>(Wq, Wk, Wv, Wo, Wqb);

  gemm_qkv<<<dim3(32, 8, 3), blk, 0, stream>>>(xb, Wqb, bq, bk, bv, Qh);

  attn_fused<<<dim3(32, 16), blk, 0, stream>>>(Qh, Kh, Vh, Yb);

  gemm_out<<<dim3(32, 16), blk, 0, stream>>>(Yb, Wob, bo, (float*)d_out);
}

// Round 16
// 148.156 us; speedup vs baseline: 1.0250x; 1.0250x over previous
//
#include <hip/hip_runtime.h>
#include <math.h>

typedef __bf16 bf16x8 __attribute__((ext_vector_type(8)));
typedef float f32x4 __attribute__((ext_vector_type(4)));

namespace {
constexpr int DIMC = 1024, NH = 16, HD = 64, SEQ = 2048;
constexpr float SCL2 = 0.1803368801f;  // 1/(tau*sqrt(64)) * log2(e), folded into Q
}

__device__ __forceinline__ unsigned short f2b(float f) {
  unsigned u = __float_as_uint(f);
  return (unsigned short)((u + 0x7fffu + ((u >> 16) & 1u)) >> 16);
}
__device__ __forceinline__ float b2f(unsigned short s) {
  return __uint_as_float((unsigned)s << 16);
}
__device__ __forceinline__ unsigned cvtpk(float lo, float hi) {
  unsigned r;
  asm("v_cvt_pk_bf16_f32 %0, %1, %2" : "=v"(r) : "v"(lo), "v"(hi));
  return r;
}
__device__ __forceinline__ void gld16(void* l, const void* g) {
  __builtin_amdgcn_global_load_lds(
      (const __attribute__((address_space(1))) void*)g,
      (__attribute__((address_space(3))) void*)l, 16, 0, 0);
}

// fp32 -> bf16 (RNE), 8 elements per thread
__global__ __launch_bounds__(256)
void cvt_bf16(const float* __restrict__ in, unsigned short* __restrict__ out, int n8) {
  int i = blockIdx.x * 256 + threadIdx.x;
  if (i >= n8) return;
  const float4* in4 = (const float4*)in;
  float4 a = in4[2 * i], b = in4[2 * i + 1];
  union { unsigned short u[8]; uint4 v; } r;
  r.u[0] = f2b(a.x); r.u[1] = f2b(a.y); r.u[2] = f2b(a.z); r.u[3] = f2b(a.w);
  r.u[4] = f2b(b.x); r.u[5] = f2b(b.y); r.u[6] = f2b(b.z); r.u[7] = f2b(b.w);
  ((uint4*)out)[i] = r.v;
}

// weight matrices fp32 -> bf16, outputs contiguous
__global__ __launch_bounds__(256)
void cvt_w4(const float* __restrict__ w0, const float* __restrict__ w1,
            const float* __restrict__ w2, const float* __restrict__ w3,
            unsigned short* __restrict__ out) {
  const int which = blockIdx.y;
  const float* src = which == 0 ? w0 : which == 1 ? w1 : which == 2 ? w2 : w3;
  unsigned short* dst = out + (size_t)which * 1048576;
  int i = blockIdx.x * 256 + threadIdx.x;
  const float4* in4 = (const float4*)src;
  float4 a = in4[2 * i], b = in4[2 * i + 1];
  union { unsigned short u[8]; uint4 v; } r;
  r.u[0] = f2b(a.x); r.u[1] = f2b(a.y); r.u[2] = f2b(a.z); r.u[3] = f2b(a.w);
  r.u[4] = f2b(b.x); r.u[5] = f2b(b.y); r.u[6] = f2b(b.z); r.u[7] = f2b(b.w);
  ((uint4*)dst)[i] = r.v;
}

// ---- m97-structure GEMM tile: BM=BN=128, BK=32, gld16 staging, 16 MFMA/K-step ----
template<int MODE>
__device__ __forceinline__
void gemm_tile128(const unsigned short* __restrict__ A, const unsigned short* __restrict__ W,
                  const float* __restrict__ bias, void* __restrict__ Cout,
                  int bm, int bn, float scl, char* As, char* Bs) {
  const int tid = threadIdx.x, lane = tid & 63, w = tid >> 6;
  const int p = lane & 15, g = lane >> 4;
  const int wr = w >> 1, wc = w & 1;
  const int sr = tid >> 2, sc = (tid & 3) * 8;

  f32x4 acc[4][4];
#pragma unroll
  for (int mf = 0; mf < 4; ++mf)
#pragma unroll
    for (int nf = 0; nf < 4; ++nf)
      acc[mf][nf] = (f32x4){0.f, 0.f, 0.f, 0.f};

  const size_t arow0 = (size_t)(bm + sr) * DIMC + sc;
  const size_t arow1 = (size_t)(bm + 64 + sr) * DIMC + sc;
  const size_t brow0 = (size_t)(bn + sr) * DIMC + sc;
  const size_t brow1 = (size_t)(bn + 64 + sr) * DIMC + sc;

  for (int k0 = 0; k0 < DIMC; k0 += 32) {
    __syncthreads();
    gld16(&As[tid * 16],        &A[arow0 + k0]);
    gld16(&As[4096 + tid * 16], &A[arow1 + k0]);
    gld16(&Bs[tid * 16],        &W[brow0 + k0]);
    gld16(&Bs[4096 + tid * 16], &W[brow1 + k0]);
    __syncthreads();
    bf16x8 af[4], bfr[4];
#pragma unroll
    for (int mf = 0; mf < 4; ++mf)
      af[mf] = *(const bf16x8*)&As[(wr * 64 + mf * 16 + p) * 64 + g * 16];
#pragma unroll
    for (int nf = 0; nf < 4; ++nf)
      bfr[nf] = *(const bf16x8*)&Bs[(wc * 64 + nf * 16 + p) * 64 + g * 16];
#pragma unroll
    for (int mf = 0; mf < 4; ++mf)
#pragma unroll
      for (int nf = 0; nf < 4; ++nf)
        acc[mf][nf] = __builtin_amdgcn_mfma_f32_16x16x32_bf16(af[mf], bfr[nf], acc[mf][nf], 0, 0, 0);
  }

#pragma unroll
  for (int nf = 0; nf < 4; ++nf) {
    const int cg = bn + wc * 64 + nf * 16 + p;
    const float bv = bias[cg & (DIMC - 1)];
#pragma unroll
    for (int mf = 0; mf < 4; ++mf) {
#pragma unroll
      for (int j = 0; j < 4; ++j) {
        const int rg = bm + wr * 64 + mf * 16 + g * 4 + j;
        const float v = (acc[mf][nf][j] + bv) * scl;
        if (MODE == 0) {
          ((float*)Cout)[(size_t)rg * DIMC + cg] = v;
        } else {
          const int bb = rg >> 11, ss = rg & (SEQ - 1);
          const int hh = cg >> 6, dd = cg & (HD - 1);
          ((unsigned short*)Cout)[(((size_t)(bb * NH + hh) * SEQ + ss) * HD) + dd] = f2b(v);
        }
      }
    }
  }
}

// fused Q/K/V projection: grid (32, 8, 3); z selects weight/bias/out.
__global__ __launch_bounds__(256, 2)
void gemm_qkv(const unsigned short* __restrict__ A, const unsigned short* __restrict__ Wall,
              const float* __restrict__ bq, const float* __restrict__ bk,
              const float* __restrict__ bv, unsigned short* __restrict__ Out) {
  __shared__ char As[8192];
  __shared__ char Bs[8192];
  const int which = blockIdx.z;
  const unsigned short* W = Wall + (size_t)which * 1048576;
  const float* bias = which == 0 ? bq : which == 1 ? bk : bv;
  unsigned short* Cout = Out + (size_t)which * 4194304;
  const float scl = which == 0 ? SCL2 : 1.0f;
  gemm_tile128<1>(A, W, bias, Cout, blockIdx.x * 128, blockIdx.y * 128, scl, As, Bs);
}

// ---- gemm_out: 128x64 tile, gld16 staging, 512 blocks = 2/CU ----
__global__ __launch_bounds__(256, 2)
void gemm_out(const unsigned short* __restrict__ A, const unsigned short* __restrict__ W,
              const float* __restrict__ bias, float* __restrict__ Cout) {
  __shared__ char As[8192];  // [128][32] bf16
  __shared__ char Bs[4096];  // [64][32] bf16
  const int tid = threadIdx.x, lane = tid & 63, w = tid >> 6;
  const int p = lane & 15, g = lane >> 4;
  const int wr = w >> 1, wc = w & 1;
  const int bm = blockIdx.x * 128, bn = blockIdx.y * 64;
  const int sr = tid >> 2, sc = (tid & 3) * 8;

  f32x4 acc[4][2];
#pragma unroll
  for (int mf = 0; mf < 4; ++mf)
#pragma unroll
    for (int nf = 0; nf < 2; ++nf)
      acc[mf][nf] = (f32x4){0.f, 0.f, 0.f, 0.f};

  const size_t arow0 = (size_t)(bm + sr) * DIMC + sc;
  const size_t arow1 = (size_t)(bm + 64 + sr) * DIMC + sc;
  const size_t brow  = (size_t)(bn + sr) * DIMC + sc;

  for (int k0 = 0; k0 < DIMC; k0 += 32) {
    __syncthreads();
    gld16(&As[tid * 16],        &A[arow0 + k0]);
    gld16(&As[4096 + tid * 16], &A[arow1 + k0]);
    gld16(&Bs[tid * 16],        &W[brow + k0]);
    __syncthreads();
    bf16x8 af[4], bfr[2];
#pragma unroll
    for (int mf = 0; mf < 4; ++mf)
      af[mf] = *(const bf16x8*)&As[(wr * 64 + mf * 16 + p) * 64 + g * 16];
#pragma unroll
    for (int nf = 0; nf < 2; ++nf)
      bfr[nf] = *(const bf16x8*)&Bs[(wc * 32 + nf * 16 + p) * 64 + g * 16];
#pragma unroll
    for (int mf = 0; mf < 4; ++mf)
#pragma unroll
      for (int nf = 0; nf < 2; ++nf)
        acc[mf][nf] = __builtin_amdgcn_mfma_f32_16x16x32_bf16(af[mf], bfr[nf], acc[mf][nf], 0, 0, 0);
  }

#pragma unroll
  for (int nf = 0; nf < 2; ++nf) {
    const int cg = bn + wc * 32 + nf * 16 + p;
    const float bv = bias[cg];
#pragma unroll
    for (int mf = 0; mf < 4; ++mf) {
#pragma unroll
      for (int j = 0; j < 4; ++j) {
        const int rg = bm + wr * 64 + mf * 16 + g * 4 + j;
        Cout[(size_t)rg * DIMC + cg] = acc[mf][nf][j] + bv;
      }
    }
  }
}

// Fused flash attention, ZERO-barrier main loop.
// Wave w = (q-half qg = w&1, key-strip kst = w>>1): 64 q-rows x 1024 keys,
// fully independent (no-max softmax => disjoint-key results merge ADDITIVELY).
// Per-wave private LDS (P 8KB + V^T 8KB); all LDS deps same-wave (lgkmcnt only).
// One barrier total: strip-1 waves dump o2/ol, strip-0 waves add + epilogue.
__global__ __launch_bounds__(256, 2)
void attn_fused(const unsigned short* __restrict__ Q, const unsigned short* __restrict__ K,
                const unsigned short* __restrict__ V, unsigned short* __restrict__ Y) {
  __shared__ char lds[73728];  // 4 x 16KB wave regions + 8KB ol-merge
  const int tid = threadIdx.x, lane = tid & 63, w = tid >> 6;
  const int p = lane & 15, g = lane >> 4;
  const int bh = blockIdx.x, b = bh >> 4, h = bh & 15;
  const int q0 = blockIdx.y * 128;
  const int qg = w & 1, kst = w >> 1;
  const int qwv = q0 + qg * 64;       // wave's 64 q-rows
  const size_t base = (size_t)bh * SEQ * HD;
  const unsigned short* Qp = Q + base;
  const unsigned short* Kp = K + base;
  const unsigned short* Vp = V + base;

  char* myPl = lds + w * 16384;        // P  [64 q][64 key] bf16, swizzled
  char* myVt = lds + w * 16384 + 8192; // V^T[64 d][64 key] bf16, swizzled

  union Vu { bf16x8 v; unsigned short u[8]; };

  // Q fragments (resident): q = qwv + mi*16 + p, k(d) = ks*32 + g*8 + j
  bf16x8 qf[4][2];
#pragma unroll
  for (int mi = 0; mi < 4; ++mi)
#pragma unroll
    for (int ks = 0; ks < 2; ++ks)
      qf[mi][ks] = *(const bf16x8*)&Qp[(size_t)(qwv + mi * 16 + p) * HD + ks * 32 + g * 8];

  bf16x8 ones8;
  {
    union { unsigned short u[8]; bf16x8 v; } o;
#pragma unroll
    for (int e = 0; e < 8; ++e) o.u[e] = (p == 0) ? (unsigned short)0x3F80 : (unsigned short)0;
    ones8 = o.v;
  }

  // strength-reduced global bases (advance 64*HD = 4096 elems/tile)
  const int kp = lane & 31, dgrp = lane >> 5;
  const unsigned short* kA = Kp + (size_t)kst * 1024 * HD + (size_t)p * HD + g * 8;
  const unsigned short* vP = Vp + (size_t)kst * 1024 * HD + (size_t)(2 * kp) * HD + dgrp * 8;

  // LDS column constants (all swizzles use (p&7) or e as the XOR row-bits)
  const int swz = (p & 7) << 4;
  int pwCol[4], sCol[2], colE[8];
#pragma unroll
  for (int nf = 0; nf < 4; ++nf) pwCol[nf] = (nf * 32 + g * 8) ^ swz;
#pragma unroll
  for (int ks = 0; ks < 2; ++ks) sCol[ks] = (ks * 64 + g * 16) ^ swz;
#pragma unroll
  for (int e = 0; e < 8; ++e) colE[e] = (kp * 4) ^ (e << 4);
  char* vtD = myVt + dgrp * 1024;   // d = dgrp*8 + c*16 + e -> d*128 = dgrp*1024 + c*2048 + e*128

  f32x4 o2[4][4];
  f32x4 ol[4];
#pragma unroll
  for (int mi = 0; mi < 4; ++mi) {
#pragma unroll
    for (int nf = 0; nf < 4; ++nf)
      o2[mi][nf] = (f32x4){0.f, 0.f, 0.f, 0.f};
    ol[mi] = (f32x4){0.f, 0.f, 0.f, 0.f};
  }

  bf16x8 kf[4][2];
  Vu vv[4][2];

  auto loadKV = [&]() {
    kf[0][0] = *(const bf16x8*)(kA + 0);    kf[0][1] = *(const bf16x8*)(kA + 32);
    kf[1][0] = *(const bf16x8*)(kA + 1024); kf[1][1] = *(const bf16x8*)(kA + 1056);
    kf[2][0] = *(const bf16x8*)(kA + 2048); kf[2][1] = *(const bf16x8*)(kA + 2080);
    kf[3][0] = *(const bf16x8*)(kA + 3072); kf[3][1] = *(const bf16x8*)(kA + 3104);
#pragma unroll
    for (int c = 0; c < 4; ++c) {
      vv[c][0].v = *(const bf16x8*)(vP + c * 16);
      vv[c][1].v = *(const bf16x8*)(vP + HD + c * 16);
    }
    kA += 4096; vP += 4096;
  };
  // qkt+softmax+P-stage, one mi at a time (keeps s transient at 16 regs)
  auto scoreStage = [&]() {
#pragma unroll
    for (int mi = 0; mi < 4; ++mi) {
      f32x4 s[4];
#pragma unroll
      for (int nf = 0; nf < 4; ++nf) s[nf] = (f32x4){0.f, 0.f, 0.f, 0.f};
      __builtin_amdgcn_s_setprio(1);
#pragma unroll
      for (int nf = 0; nf < 4; ++nf)
#pragma unroll
        for (int ks = 0; ks < 2; ++ks)
          s[nf] = __builtin_amdgcn_mfma_f32_16x16x32_bf16(kf[nf][ks], qf[mi][ks], s[nf], 0, 0, 0);
      __builtin_amdgcn_s_setprio(0);
#pragma unroll
      for (int nf = 0; nf < 4; ++nf)
#pragma unroll
        for (int j = 0; j < 4; ++j)
          s[nf][j] = exp2f(s[nf][j]);
#pragma unroll
      for (int nf = 0; nf < 4; ++nf) {
        uint2 val;
        val.x = cvtpk(s[nf][0], s[nf][1]);
        val.y = cvtpk(s[nf][2], s[nf][3]);
        *(uint2*)(myPl + p * 128 + mi * 2048 + pwCol[nf]) = val;
      }
    }
  };
  auto stageVt = [&]() {
#pragma unroll
    for (int c = 0; c < 4; ++c)
#pragma unroll
      for (int e = 0; e < 8; ++e) {
        const unsigned val = (unsigned)vv[c][0].u[e] | ((unsigned)vv[c][1].u[e] << 16);
        *(unsigned*)(vtD + c * 2048 + e * 128 + colE[e]) = val;
      }
  };
  auto pv = [&]() {
    bf16x8 vb[4][2];
#pragma unroll
    for (int nfd = 0; nfd < 4; ++nfd)
#pragma unroll
      for (int ks = 0; ks < 2; ++ks)
        vb[nfd][ks] = *(const bf16x8*)(myVt + p * 128 + nfd * 2048 + sCol[ks]);
#pragma unroll
    for (int mi = 0; mi < 4; ++mi) {
      bf16x8 pf[2];
#pragma unroll
      for (int ks = 0; ks < 2; ++ks)
        pf[ks] = *(const bf16x8*)(myPl + p * 128 + mi * 2048 + sCol[ks]);
      __builtin_amdgcn_s_setprio(1);
#pragma unroll
      for (int nfd = 0; nfd < 4; ++nfd)
#pragma unroll
        for (int ks = 0; ks < 2; ++ks)
          o2[mi][nfd] = __builtin_amdgcn_mfma_f32_16x16x32_bf16(vb[nfd][ks], pf[ks], o2[mi][nfd], 0, 0, 0);
#pragma unroll
      for (int ks = 0; ks < 2; ++ks)
        ol[mi] = __builtin_amdgcn_mfma_f32_16x16x32_bf16(ones8, pf[ks], ol[mi], 0, 0, 0);
      __builtin_amdgcn_s_setprio(0);
    }
  };

  // ---- zero-barrier pipelined loop over this wave's 16 key-tiles ----
  loadKV();
  scoreStage();
  stageVt();
  for (int kt = 1; kt < 16; ++kt) {
    loadKV();      // K/V(t) in flight...
    pv();          // ...hidden under PV(t-1) (LDS reads + MFMA)
    scoreStage();  // QK^T(t) + softmax + P-stage (same-wave LDS, lgkmcnt only)
    stageVt();     // V(t) -> LDS (after pv's reads; compiler WAR via lgkmcnt)
  }
  pv();

  // ---- merge strips (additive: no-max softmax) ----
  if (kst == 1) {
    char* dst = lds + w * 16384;         // own region, reusable now
#pragma unroll
    for (int mi = 0; mi < 4; ++mi)
#pragma unroll
      for (int nfd = 0; nfd < 4; ++nfd)
        *(f32x4*)(dst + (mi * 4 + nfd) * 1024 + lane * 16) = o2[mi][nfd];
    char* dsl = lds + 65536 + (w - 2) * 4096;
#pragma unroll
    for (int mi = 0; mi < 4; ++mi)
      *(f32x4*)(dsl + mi * 1024 + lane * 16) = ol[mi];
  }
  __syncthreads();
  if (kst == 1) return;

  {
    const char* src = lds + (w + 2) * 16384;
#pragma unroll
    for (int mi = 0; mi < 4; ++mi)
#pragma unroll
      for (int nfd = 0; nfd < 4; ++nfd)
        o2[mi][nfd] += *(const f32x4*)(src + (mi * 4 + nfd) * 1024 + lane * 16);
    const char* sl = lds + 65536 + w * 4096;
#pragma unroll
    for (int mi = 0; mi < 4; ++mi)
      ol[mi] += *(const f32x4*)(sl + mi * 1024 + lane * 16);
  }

  // epilogue: out = 0.6*O/l + 0.4*(L@V); l broadcast from (g==0) lanes
  const float e1 = 4.3936934e-2f, e2 = 3.7266532e-6f, e3 = 6.1019804e-13f;
  const float lwv[4] = {1.f, e1, e2, e3};
#pragma unroll
  for (int mi = 0; mi < 4; ++mi) {
    const int q = qwv + mi * 16 + p;
    const float lq = __shfl(ol[mi][0], p);   // lane (g=0, p) holds row-0 sum for q
    const float inv = 0.6f / lq;
    float wsum = 0.f;
#pragma unroll
    for (int dd = -3; dd <= 3; ++dd) {
      const int kk = q + dd;
      if (kk >= 0 && kk < SEQ) wsum += lwv[dd < 0 ? -dd : dd];
    }
    const float wn = 0.4f / (wsum + 1e-10f);
#pragma unroll
    for (int nfd = 0; nfd < 4; ++nfd) {
      const int d0 = nfd * 16 + g * 4;
      float loc[4] = {0.f, 0.f, 0.f, 0.f};
#pragma unroll
      for (int dd = -3; dd <= 3; ++dd) {
        const int kk = q + dd;
        if (kk >= 0 && kk < SEQ) {
          const uint2 lv = *(const uint2*)&Vp[(size_t)kk * HD + d0];
          const float wt = lwv[dd < 0 ? -dd : dd];
          loc[0] = fmaf(wt, b2f((unsigned short)lv.x), loc[0]);
          loc[1] = fmaf(wt, b2f((unsigned short)(lv.x >> 16)), loc[1]);
          loc[2] = fmaf(wt, b2f((unsigned short)lv.y), loc[2]);
          loc[3] = fmaf(wt, b2f((unsigned short)(lv.y >> 16)), loc[3]);
        }
      }
      uint2 st;
      st.x = cvtpk(o2[mi][nfd][0] * inv + loc[0] * wn, o2[mi][nfd][1] * inv + loc[1] * wn);
      st.y = cvtpk(o2[mi][nfd][2] * inv + loc[2] * wn, o2[mi][nfd][3] * inv + loc[3] * wn);
      *(uint2*)&Y[((size_t)(b * SEQ + q)) * DIMC + h * HD + d0] = st;
    }
  }
}

extern "C" void kernel_launch(void* const* d_in, const int* in_sizes, int n_in,
                              void* d_out, int out_size, void* d_ws, size_t ws_size,
                              hipStream_t stream) {
  (void)in_sizes; (void)n_in; (void)out_size; (void)ws_size;
  const float* x  = (const float*)d_in[0];
  const float* Wq = (const float*)d_in[1];
  const float* bq = (const float*)d_in[2];
  const float* Wk = (const float*)d_in[3];
  const float* bk = (const float*)d_in[4];
  const float* Wv = (const float*)d_in[5];
  const float* bv = (const float*)d_in[6];
  const float* Wo = (const float*)d_in[7];
  const float* bo = (const float*)d_in[8];

  char* ws = (char*)d_ws;
  unsigned short* xb  = (unsigned short*)(ws);               // 8 MB
  unsigned short* Wqb = (unsigned short*)(ws + 8388608);     // 2 MB each, contiguous
  unsigned short* Wob = (unsigned short*)(ws + 14680064);
  unsigned short* Qh  = (unsigned short*)(ws + 16777216);    // 8 MB each (Q,K,V)
  unsigned short* Kh  = (unsigned short*)(ws + 25165824);
  unsigned short* Vh  = (unsigned short*)(ws + 33554432);
  unsigned short* Yb  = (unsigned short*)(ws + 41943040);    // 8 MB

  dim3 blk(256);
  cvt_bf16<<<2048, blk, 0, stream>>>(x, xb, 524288);
  cvt_w4<<<dim3(512, 4), blk, 0, stream>>>(Wq, Wk, Wv, Wo, Wqb);

  gemm_qkv<<<dim3(32, 8, 3), blk, 0, stream>>>(xb, Wqb, bq, bk, bv, Qh);

  attn_fused<<<dim3(32, 16), blk, 0, stream>>>(Qh, Kh, Vh, Yb);

  gemm_out<<<dim3(32, 16), blk, 0, stream>>>(Yb, Wob, bo, (float*)d_out);
}

// Round 17
// 129.382 us; speedup vs baseline: 1.1737x; 1.1451x over previous
//
#include <hip/hip_runtime.h>
#include <math.h>

typedef __bf16 bf16x8 __attribute__((ext_vector_type(8)));
typedef float f32x4 __attribute__((ext_vector_type(4)));

namespace {
constexpr int DIMC = 1024, NH = 16, HD = 64, SEQ = 2048;
constexpr float SCL2 = 0.1803368801f;  // 1/(tau*sqrt(64)) * log2(e), folded into Q
}

__device__ __forceinline__ unsigned short f2b(float f) {
  unsigned u = __float_as_uint(f);
  return (unsigned short)((u + 0x7fffu + ((u >> 16) & 1u)) >> 16);
}
__device__ __forceinline__ float b2f(unsigned short s) {
  return __uint_as_float((unsigned)s << 16);
}
__device__ __forceinline__ unsigned cvtpk(float lo, float hi) {
  unsigned r;
  asm("v_cvt_pk_bf16_f32 %0, %1, %2" : "=v"(r) : "v"(lo), "v"(hi));
  return r;
}
__device__ __forceinline__ void gld16(void* l, const void* g) {
  __builtin_amdgcn_global_load_lds(
      (const __attribute__((address_space(1))) void*)g,
      (__attribute__((address_space(3))) void*)l, 16, 0, 0);
}

// fp32 -> bf16 (RNE), 8 elements per thread
__global__ __launch_bounds__(256)
void cvt_bf16(const float* __restrict__ in, unsigned short* __restrict__ out, int n8) {
  int i = blockIdx.x * 256 + threadIdx.x;
  if (i >= n8) return;
  const float4* in4 = (const float4*)in;
  float4 a = in4[2 * i], b = in4[2 * i + 1];
  union { unsigned short u[8]; uint4 v; } r;
  r.u[0] = f2b(a.x); r.u[1] = f2b(a.y); r.u[2] = f2b(a.z); r.u[3] = f2b(a.w);
  r.u[4] = f2b(b.x); r.u[5] = f2b(b.y); r.u[6] = f2b(b.z); r.u[7] = f2b(b.w);
  ((uint4*)out)[i] = r.v;
}

// weight matrices fp32 -> bf16, outputs contiguous
__global__ __launch_bounds__(256)
void cvt_w4(const float* __restrict__ w0, const float* __restrict__ w1,
            const float* __restrict__ w2, const float* __restrict__ w3,
            unsigned short* __restrict__ out) {
  const int which = blockIdx.y;
  const float* src = which == 0 ? w0 : which == 1 ? w1 : which == 2 ? w2 : w3;
  unsigned short* dst = out + (size_t)which * 1048576;
  int i = blockIdx.x * 256 + threadIdx.x;
  const float4* in4 = (const float4*)src;
  float4 a = in4[2 * i], b = in4[2 * i + 1];
  union { unsigned short u[8]; uint4 v; } r;
  r.u[0] = f2b(a.x); r.u[1] = f2b(a.y); r.u[2] = f2b(a.z); r.u[3] = f2b(a.w);
  r.u[4] = f2b(b.x); r.u[5] = f2b(b.y); r.u[6] = f2b(b.z); r.u[7] = f2b(b.w);
  ((uint4*)dst)[i] = r.v;
}

// ---- m97-structure GEMM tile: BM=BN=128, BK=32, gld16 staging, 16 MFMA/K-step ----
// kswz: write K rows with d ^= ((seq&7)<<3) so the attention kernel's linear
// gld16 staging + swizzled ds_read is bank-conflict-free (both-sides rule).
template<int MODE>
__device__ __forceinline__
void gemm_tile128(const unsigned short* __restrict__ A, const unsigned short* __restrict__ W,
                  const float* __restrict__ bias, void* __restrict__ Cout,
                  int bm, int bn, float scl, bool kswz, char* As, char* Bs) {
  const int tid = threadIdx.x, lane = tid & 63, w = tid >> 6;
  const int p = lane & 15, g = lane >> 4;
  const int wr = w >> 1, wc = w & 1;
  const int sr = tid >> 2, sc = (tid & 3) * 8;

  f32x4 acc[4][4];
#pragma unroll
  for (int mf = 0; mf < 4; ++mf)
#pragma unroll
    for (int nf = 0; nf < 4; ++nf)
      acc[mf][nf] = (f32x4){0.f, 0.f, 0.f, 0.f};

  const size_t arow0 = (size_t)(bm + sr) * DIMC + sc;
  const size_t arow1 = (size_t)(bm + 64 + sr) * DIMC + sc;
  const size_t brow0 = (size_t)(bn + sr) * DIMC + sc;
  const size_t brow1 = (size_t)(bn + 64 + sr) * DIMC + sc;

  for (int k0 = 0; k0 < DIMC; k0 += 32) {
    __syncthreads();
    gld16(&As[tid * 16],        &A[arow0 + k0]);
    gld16(&As[4096 + tid * 16], &A[arow1 + k0]);
    gld16(&Bs[tid * 16],        &W[brow0 + k0]);
    gld16(&Bs[4096 + tid * 16], &W[brow1 + k0]);
    __syncthreads();
    bf16x8 af[4], bfr[4];
#pragma unroll
    for (int mf = 0; mf < 4; ++mf)
      af[mf] = *(const bf16x8*)&As[(wr * 64 + mf * 16 + p) * 64 + g * 16];
#pragma unroll
    for (int nf = 0; nf < 4; ++nf)
      bfr[nf] = *(const bf16x8*)&Bs[(wc * 64 + nf * 16 + p) * 64 + g * 16];
#pragma unroll
    for (int mf = 0; mf < 4; ++mf)
#pragma unroll
      for (int nf = 0; nf < 4; ++nf)
        acc[mf][nf] = __builtin_amdgcn_mfma_f32_16x16x32_bf16(af[mf], bfr[nf], acc[mf][nf], 0, 0, 0);
  }

#pragma unroll
  for (int nf = 0; nf < 4; ++nf) {
    const int cg = bn + wc * 64 + nf * 16 + p;
    const float bv = bias[cg & (DIMC - 1)];
#pragma unroll
    for (int mf = 0; mf < 4; ++mf) {
#pragma unroll
      for (int j = 0; j < 4; ++j) {
        const int rg = bm + wr * 64 + mf * 16 + g * 4 + j;
        const float v = (acc[mf][nf][j] + bv) * scl;
        if (MODE == 0) {
          ((float*)Cout)[(size_t)rg * DIMC + cg] = v;
        } else {
          const int bb = rg >> 11, ss = rg & (SEQ - 1);
          const int hh = cg >> 6;
          int dd = cg & (HD - 1);
          if (kswz) dd ^= (ss & 7) << 3;
          ((unsigned short*)Cout)[(((size_t)(bb * NH + hh) * SEQ + ss) * HD) + dd] = f2b(v);
        }
      }
    }
  }
}

// fused Q/K/V projection: grid (32, 8, 3); z selects weight/bias/out.
// Q pre-scaled by SCL2; K written row-swizzled for the attention staging.
__global__ __launch_bounds__(256, 2)
void gemm_qkv(const unsigned short* __restrict__ A, const unsigned short* __restrict__ Wall,
              const float* __restrict__ bq, const float* __restrict__ bk,
              const float* __restrict__ bv, unsigned short* __restrict__ Out) {
  __shared__ char As[8192];
  __shared__ char Bs[8192];
  const int which = blockIdx.z;
  const unsigned short* W = Wall + (size_t)which * 1048576;
  const float* bias = which == 0 ? bq : which == 1 ? bk : bv;
  unsigned short* Cout = Out + (size_t)which * 4194304;
  const float scl = which == 0 ? SCL2 : 1.0f;
  gemm_tile128<1>(A, W, bias, Cout, blockIdx.x * 128, blockIdx.y * 128, scl, which == 1, As, Bs);
}

// ---- gemm_out: 128x64 tile, gld16 staging, 512 blocks = 2/CU ----
__global__ __launch_bounds__(256, 2)
void gemm_out(const unsigned short* __restrict__ A, const unsigned short* __restrict__ W,
              const float* __restrict__ bias, float* __restrict__ Cout) {
  __shared__ char As[8192];  // [128][32] bf16
  __shared__ char Bs[4096];  // [64][32] bf16
  const int tid = threadIdx.x, lane = tid & 63, w = tid >> 6;
  const int p = lane & 15, g = lane >> 4;
  const int wr = w >> 1, wc = w & 1;
  const int bm = blockIdx.x * 128, bn = blockIdx.y * 64;
  const int sr = tid >> 2, sc = (tid & 3) * 8;

  f32x4 acc[4][2];
#pragma unroll
  for (int mf = 0; mf < 4; ++mf)
#pragma unroll
    for (int nf = 0; nf < 2; ++nf)
      acc[mf][nf] = (f32x4){0.f, 0.f, 0.f, 0.f};

  const size_t arow0 = (size_t)(bm + sr) * DIMC + sc;
  const size_t arow1 = (size_t)(bm + 64 + sr) * DIMC + sc;
  const size_t brow  = (size_t)(bn + sr) * DIMC + sc;

  for (int k0 = 0; k0 < DIMC; k0 += 32) {
    __syncthreads();
    gld16(&As[tid * 16],        &A[arow0 + k0]);
    gld16(&As[4096 + tid * 16], &A[arow1 + k0]);
    gld16(&Bs[tid * 16],        &W[brow + k0]);
    __syncthreads();
    bf16x8 af[4], bfr[2];
#pragma unroll
    for (int mf = 0; mf < 4; ++mf)
      af[mf] = *(const bf16x8*)&As[(wr * 64 + mf * 16 + p) * 64 + g * 16];
#pragma unroll
    for (int nf = 0; nf < 2; ++nf)
      bfr[nf] = *(const bf16x8*)&Bs[(wc * 32 + nf * 16 + p) * 64 + g * 16];
#pragma unroll
    for (int mf = 0; mf < 4; ++mf)
#pragma unroll
      for (int nf = 0; nf < 2; ++nf)
        acc[mf][nf] = __builtin_amdgcn_mfma_f32_16x16x32_bf16(af[mf], bfr[nf], acc[mf][nf], 0, 0, 0);
  }

#pragma unroll
  for (int nf = 0; nf < 2; ++nf) {
    const int cg = bn + wc * 32 + nf * 16 + p;
    const float bv = bias[cg];
#pragma unroll
    for (int mf = 0; mf < 4; ++mf) {
#pragma unroll
      for (int j = 0; j < 4; ++j) {
        const int rg = bm + wr * 64 + mf * 16 + g * 4 + j;
        Cout[(size_t)rg * DIMC + cg] = acc[mf][nf][j] + bv;
      }
    }
  }
}

// Fused flash attention, shared-KV staging (gld16 K, reg-staged V), 8 waves x
// 16 q-rows, one barrier/tile, dbuf K/V, wave-private P. 4 waves/SIMD.
__global__ __launch_bounds__(512, 4)
void attn_fused(const unsigned short* __restrict__ Q, const unsigned short* __restrict__ K,
                const unsigned short* __restrict__ V, unsigned short* __restrict__ Y) {
  __shared__ char Kl[2][8192];   // K tile [64 key][64 d] bf16, pre-swizzled rows
  __shared__ char Vt[2][8192];   // V^T [64 d][64 key] bf16, XOR-swizzled
  __shared__ char Pl[16384];     // per-wave P [16 q][64 key] bf16 (8 x 2KB)
  const int tid = threadIdx.x, lane = tid & 63, w = tid >> 6;
  const int p = lane & 15, g = lane >> 4;
  const int bh = blockIdx.x, b = bh >> 4, h = bh & 15;
  const int q0 = blockIdx.y * 128;
  const int qwv = q0 + w * 16;
  const size_t base = (size_t)bh * SEQ * HD;
  const unsigned short* Qp = Q + base;
  const unsigned short* Kp = K + base;   // row-swizzled by gemm_qkv
  const unsigned short* Vp = V + base;

  union Vu { bf16x8 v; unsigned short u[8]; };

  // Q fragments: q = qwv + p, k(d) = ks*32 + g*8 + j
  bf16x8 qf[2];
#pragma unroll
  for (int ks = 0; ks < 2; ++ks)
    qf[ks] = *(const bf16x8*)&Qp[(size_t)(qwv + p) * HD + ks * 32 + g * 8];

  bf16x8 ones8;
  {
    union { unsigned short u[8]; bf16x8 v; } o;
#pragma unroll
    for (int e = 0; e < 8; ++e) o.u[e] = (p == 0) ? (unsigned short)0x3F80 : (unsigned short)0;
    ones8 = o.v;
  }

  // K staging: thread stages 16B of row tid>>3 (wave-uniform base + lane*16)
  const unsigned short* kSrc = Kp + (size_t)(tid >> 3) * HD + (tid & 7) * 8;
  // V staging: threads < 256 handle (key-pair kp, 8-d group vd0)
  const int kp = tid & 31, vd0 = ((tid >> 5) & 7) * 8;
  const bool vload = tid < 256;
  const unsigned short* vSrc = Vp + (size_t)(2 * kp) * HD + vd0;

  const int swz = (p & 7) << 4;
  int sCol[2], pwCol[4], colE[8];
#pragma unroll
  for (int ks = 0; ks < 2; ++ks) sCol[ks] = (ks * 64 + g * 16) ^ swz;
#pragma unroll
  for (int nf = 0; nf < 4; ++nf) pwCol[nf] = (nf * 32 + g * 8) ^ swz;
#pragma unroll
  for (int e = 0; e < 8; ++e) colE[e] = (kp * 4) ^ (e << 4);

  f32x4 o2[4];   // O^T frags: col q = p, row d = nfd*16 + g*4 + j
  f32x4 ol;      // l: row 0 (g==0,j==0), col q = p
#pragma unroll
  for (int nf = 0; nf < 4; ++nf) o2[nf] = (f32x4){0.f, 0.f, 0.f, 0.f};
  ol = (f32x4){0.f, 0.f, 0.f, 0.f};

  Vu v0A, v1A, v0B, v1B;

  auto gldK = [&](int par, int kb) {
    gld16(&Kl[par][tid * 16], kSrc + (size_t)kb * HD);
  };
  auto loadV = [&](Vu& a0, Vu& a1, int kb) {
    if (vload) {
      a0.v = *(const bf16x8*)(vSrc + (size_t)kb * HD);
      a1.v = *(const bf16x8*)(vSrc + (size_t)(kb + 1) * HD);
    }
  };
  auto writeV = [&](int par, Vu& a0, Vu& a1) {
    if (vload) {
      char* vtp = &Vt[par][0] + vd0 * 128;
#pragma unroll
      for (int e = 0; e < 8; ++e) {
        const unsigned val = (unsigned)a0.u[e] | ((unsigned)a1.u[e] << 16);
        *(unsigned*)(vtp + e * 128 + colE[e]) = val;
      }
    }
  };
  auto qkt_sm_stage = [&](int par) {
    const char* klp = &Kl[par][0] + p * 128;
    bf16x8 kf[4][2];
#pragma unroll
    for (int nf = 0; nf < 4; ++nf)
#pragma unroll
      for (int ks = 0; ks < 2; ++ks)
        kf[nf][ks] = *(const bf16x8*)(klp + nf * 2048 + sCol[ks]);
    f32x4 s[4];
#pragma unroll
    for (int nf = 0; nf < 4; ++nf) s[nf] = (f32x4){0.f, 0.f, 0.f, 0.f};
    __builtin_amdgcn_s_setprio(1);
#pragma unroll
    for (int nf = 0; nf < 4; ++nf)
#pragma unroll
      for (int ks = 0; ks < 2; ++ks)
        s[nf] = __builtin_amdgcn_mfma_f32_16x16x32_bf16(kf[nf][ks], qf[ks], s[nf], 0, 0, 0);
    __builtin_amdgcn_s_setprio(0);
#pragma unroll
    for (int nf = 0; nf < 4; ++nf)
#pragma unroll
      for (int j = 0; j < 4; ++j)
        s[nf][j] = exp2f(s[nf][j]);
    char* plp = &Pl[0] + w * 2048 + p * 128;
#pragma unroll
    for (int nf = 0; nf < 4; ++nf) {
      uint2 val;
      val.x = cvtpk(s[nf][0], s[nf][1]);
      val.y = cvtpk(s[nf][2], s[nf][3]);
      *(uint2*)(plp + pwCol[nf]) = val;
    }
  };
  auto pv = [&](int par) {
    const char* plp = &Pl[0] + w * 2048 + p * 128;
    bf16x8 pf[2];
#pragma unroll
    for (int ks = 0; ks < 2; ++ks)
      pf[ks] = *(const bf16x8*)(plp + sCol[ks]);
    const char* vtp = &Vt[par][0] + p * 128;
    bf16x8 vb[4][2];
#pragma unroll
    for (int nfd = 0; nfd < 4; ++nfd)
#pragma unroll
      for (int ks = 0; ks < 2; ++ks)
        vb[nfd][ks] = *(const bf16x8*)(vtp + nfd * 2048 + sCol[ks]);
    __builtin_amdgcn_s_setprio(1);
#pragma unroll
    for (int nfd = 0; nfd < 4; ++nfd)
#pragma unroll
      for (int ks = 0; ks < 2; ++ks)
        o2[nfd] = __builtin_amdgcn_mfma_f32_16x16x32_bf16(vb[nfd][ks], pf[ks], o2[nfd], 0, 0, 0);
#pragma unroll
    for (int ks = 0; ks < 2; ++ks)
      ol = __builtin_amdgcn_mfma_f32_16x16x32_bf16(ones8, pf[ks], ol, 0, 0, 0);
    __builtin_amdgcn_s_setprio(0);
  };

  // prologue: K(0) staged, V(0) in regs
  gldK(0, 0);
  loadV(v0A, v1A, 0);
  __syncthreads();   // vmcnt drained: K(0) resident

  for (int it = 0; it < 16; ++it) {
    const int t0 = 2 * it;
    // tile t0 (buffers par=0)
    gldK(1, (t0 + 1) * 64);          // K(t0+1) DMA in flight
    loadV(v0B, v1B, (t0 + 1) * 64);  // V(t0+1) in flight
    qkt_sm_stage(0);                 // reads Kl[0]
    writeV(0, v0A, v1A);             // V(t0) -> Vt[0]
    __syncthreads();                 // Vt[0] visible; K/V(t0+1) drained
    pv(0);
    // tile t0+1 (buffers par=1)
    if (it < 15) {
      gldK(0, (t0 + 2) * 64);
      loadV(v0A, v1A, (t0 + 2) * 64);
    }
    qkt_sm_stage(1);
    writeV(1, v0B, v1B);
    __syncthreads();
    pv(1);
  }

  // epilogue: out = 0.6*O/l + 0.4*(L@V); l broadcast from (g==0) lanes
  const float e1 = 4.3936934e-2f, e2 = 3.7266532e-6f, e3 = 6.1019804e-13f;
  const float lwv[4] = {1.f, e1, e2, e3};
  {
    const int q = qwv + p;
    const float lq = __shfl(ol[0], p);   // lane (g=0, p) holds row-0 sum for q
    const float inv = 0.6f / lq;
    float wsum = 0.f;
#pragma unroll
    for (int dd = -3; dd <= 3; ++dd) {
      const int kk = q + dd;
      if (kk >= 0 && kk < SEQ) wsum += lwv[dd < 0 ? -dd : dd];
    }
    const float wn = 0.4f / (wsum + 1e-10f);
#pragma unroll
    for (int nfd = 0; nfd < 4; ++nfd) {
      const int d0 = nfd * 16 + g * 4;
      float loc[4] = {0.f, 0.f, 0.f, 0.f};
#pragma unroll
      for (int dd = -3; dd <= 3; ++dd) {
        const int kk = q + dd;
        if (kk >= 0 && kk < SEQ) {
          const uint2 lv = *(const uint2*)&Vp[(size_t)kk * HD + d0];
          const float wt = lwv[dd < 0 ? -dd : dd];
          loc[0] = fmaf(wt, b2f((unsigned short)lv.x), loc[0]);
          loc[1] = fmaf(wt, b2f((unsigned short)(lv.x >> 16)), loc[1]);
          loc[2] = fmaf(wt, b2f((unsigned short)lv.y), loc[2]);
          loc[3] = fmaf(wt, b2f((unsigned short)(lv.y >> 16)), loc[3]);
        }
      }
      uint2 st;
      st.x = cvtpk(o2[nfd][0] * inv + loc[0] * wn, o2[nfd][1] * inv + loc[1] * wn);
      st.y = cvtpk(o2[nfd][2] * inv + loc[2] * wn, o2[nfd][3] * inv + loc[3] * wn);
      *(uint2*)&Y[((size_t)(b * SEQ + q)) * DIMC + h * HD + d0] = st;
    }
  }
}

extern "C" void kernel_launch(void* const* d_in, const int* in_sizes, int n_in,
                              void* d_out, int out_size, void* d_ws, size_t ws_size,
                              hipStream_t stream) {
  (void)in_sizes; (void)n_in; (void)out_size; (void)ws_size;
  const float* x  = (const float*)d_in[0];
  const float* Wq = (const float*)d_in[1];
  const float* bq = (const float*)d_in[2];
  const float* Wk = (const float*)d_in[3];
  const float* bk = (const float*)d_in[4];
  const float* Wv = (const float*)d_in[5];
  const float* bv = (const float*)d_in[6];
  const float* Wo = (const float*)d_in[7];
  const float* bo = (const float*)d_in[8];

  char* ws = (char*)d_ws;
  unsigned short* xb  = (unsigned short*)(ws);               // 8 MB
  unsigned short* Wqb = (unsigned short*)(ws + 8388608);     // 2 MB each, contiguous
  unsigned short* Wob = (unsigned short*)(ws + 14680064);
  unsigned short* Qh  = (unsigned short*)(ws + 16777216);    // 8 MB each (Q,K,V)
  unsigned short* Kh  = (unsigned short*)(ws + 25165824);
  unsigned short* Vh  = (unsigned short*)(ws + 33554432);
  unsigned short* Yb  = (unsigned short*)(ws + 41943040);    // 8 MB

  dim3 blk(256);
  cvt_bf16<<<2048, blk, 0, stream>>>(x, xb, 524288);
  cvt_w4<<<dim3(512, 4), blk, 0, stream>>>(Wq, Wk, Wv, Wo, Wqb);

  gemm_qkv<<<dim3(32, 8, 3), blk, 0, stream>>>(xb, Wqb, bq, bk, bv, Qh);

  attn_fused<<<dim3(32, 16), dim3(512), 0, stream>>>(Qh, Kh, Vh, Yb);

  gemm_out<<<dim3(32, 16), blk, 0, stream>>>(Yb, Wob, bo, (float*)d_out);
}